// Round 1
// baseline (515.499 us; speedup 1.0000x reference)
//
#include <hip/hip_runtime.h>

#define Bn 256
#define Tn 2048
#define Pn 64

// ---------------------------------------------------------------------------
// Linear-chain CRF mean NLL.
//   nll = mean_b( logZ_b - emit_b - trans_b )
// k1 (crf_chain): 512 blocks x 64 threads. Block 2b = forward chain of batch b
//   (alpha, 1024 steps t=1..1024); block 2b+1 = backward gamma chain
//   (1022 steps t=2046..1025 + one bare matvec -> beta_1024).
//   State kept in linear space p[j] = exp(alpha[j]-C); step = f32 matvec with
//   exp(A) held per-lane in 64 VGPRs, p broadcast via LDS float4 reads.
// k2 (crf_finish): 256 blocks x 256 threads. label scores + midpoint dot +
//   block reduce + atomicAdd of nll_b/256 into d_out.
// ---------------------------------------------------------------------------

__device__ __forceinline__ float wave_max64(float v) {
#pragma unroll
    for (int off = 32; off > 0; off >>= 1)
        v = fmaxf(v, __shfl_xor(v, off, 64));
    return v;
}

__device__ __forceinline__ float wave_sum64(float v) {
#pragma unroll
    for (int off = 32; off > 0; off >>= 1)
        v += __shfl_xor(v, off, 64);
    return v;
}

__global__ __launch_bounds__(64) void crf_chain(
        const float* __restrict__ unary, const float* __restrict__ A,
        float* __restrict__ wsState, float* __restrict__ wsC) {
    const int bid = blockIdx.x;
    const int b   = bid >> 1;
    const int dir = bid & 1;   // 0 = forward, 1 = backward
    const int j   = threadIdx.x;

    __shared__ float pbuf[2][Pn] __attribute__((aligned(16)));

    // Per-lane exp(A): fwd lane j holds column j (eAr[i]=exp(A[i][j]));
    // bwd lane j holds row j (eAr[i]=exp(A[j][i])). 64 VGPRs, fully static.
    float eAr[Pn];
#pragma unroll
    for (int i = 0; i < Pn; ++i) {
        float a = (dir == 0) ? A[i * Pn + j] : A[j * Pn + i];
        eAr[i] = __expf(a);
    }

    const float* ub = unary + (size_t)b * Tn * Pn;

    // init: alpha_0 = u_0  /  gamma_{T-1} = u_{T-1}
    float p, C;
    {
        const int t0 = (dir == 0) ? 0 : (Tn - 1);
        float u0 = ub[(size_t)t0 * Pn + j];
        float m  = wave_max64(u0);
        p = __expf(u0 - m);
        C = m;
    }
    pbuf[0][j] = p;

    const int nstep = (dir == 0) ? 1024 : 1022;
    const ptrdiff_t stride = (dir == 0) ? (ptrdiff_t)Pn : -(ptrdiff_t)Pn;
    const float* up = ub + j + ((dir == 0) ? (ptrdiff_t)Pn
                                           : (ptrdiff_t)(Tn - 2) * Pn);

    // register prefetch queue, depth 4 (static indices via unroll-4)
    float uq[4];
#pragma unroll
    for (int k = 0; k < 4; ++k) uq[k] = up[stride * k];

    const int nquad = nstep >> 2;   // 256 (fwd) / 255 (bwd)
    const int nrem  = nstep & 3;    // 0 / 2

    for (int q = 0; q < nquad; ++q) {
#pragma unroll
        for (int k = 0; k < 4; ++k) {
            const int par = k & 1;                 // (4q+k)&1
            const float4* src = (const float4*)pbuf[par];
            float4 acc = make_float4(0.f, 0.f, 0.f, 0.f);
#pragma unroll
            for (int blk = 0; blk < 16; ++blk) {
                float4 pv = src[blk];              // broadcast ds_read_b128
                acc.x = fmaf(pv.x, eAr[4 * blk + 0], acc.x);
                acc.y = fmaf(pv.y, eAr[4 * blk + 1], acc.y);
                acc.z = fmaf(pv.z, eAr[4 * blk + 2], acc.z);
                acc.w = fmaf(pv.w, eAr[4 * blk + 3], acc.w);
            }
            float eu = __expf(uq[k]);
            uq[k] = up[stride * (4 + k)];          // prefetch step s+4
            p = ((acc.x + acc.y) + (acc.z + acc.w)) * eu;
            if (k == 3 && (q & 1) == 1) {          // s%8==7: renorm
                float m = wave_max64(p);
                p *= (1.0f / m);
                C += __logf(m);
            }
            pbuf[par ^ 1][j] = p;                  // publish for next step
        }
        up += stride * 4;
    }
    // remainder (bwd only: 2 steps, no prefetch reload needed)
#pragma unroll
    for (int k = 0; k < 4; ++k) {
        if (k < nrem) {
            const int par = k & 1;                 // (4*nquad+k)&1 == k&1
            const float4* src = (const float4*)pbuf[par];
            float4 acc = make_float4(0.f, 0.f, 0.f, 0.f);
#pragma unroll
            for (int blk = 0; blk < 16; ++blk) {
                float4 pv = src[blk];
                acc.x = fmaf(pv.x, eAr[4 * blk + 0], acc.x);
                acc.y = fmaf(pv.y, eAr[4 * blk + 1], acc.y);
                acc.z = fmaf(pv.z, eAr[4 * blk + 2], acc.z);
                acc.w = fmaf(pv.w, eAr[4 * blk + 3], acc.w);
            }
            float eu = __expf(uq[k]);
            p = ((acc.x + acc.y) + (acc.z + acc.w)) * eu;
            pbuf[par ^ 1][j] = p;
        }
    }
    // backward: one bare matvec (A-transition only, no emission) -> beta_1024
    if (dir == 1) {
        const int par = nstep & 1;                 // 1022 & 1 == 0
        const float4* src = (const float4*)pbuf[par];
        float4 acc = make_float4(0.f, 0.f, 0.f, 0.f);
#pragma unroll
        for (int blk = 0; blk < 16; ++blk) {
            float4 pv = src[blk];
            acc.x = fmaf(pv.x, eAr[4 * blk + 0], acc.x);
            acc.y = fmaf(pv.y, eAr[4 * blk + 1], acc.y);
            acc.z = fmaf(pv.z, eAr[4 * blk + 2], acc.z);
            acc.w = fmaf(pv.w, eAr[4 * blk + 3], acc.w);
        }
        p = (acc.x + acc.y) + (acc.z + acc.w);
    }
    // final renorm so stored states are <=1 (midpoint dot can't overflow)
    {
        float m = wave_max64(p);
        p *= (1.0f / m);
        C += __logf(m);
    }
    wsState[(size_t)bid * Pn + j] = p;
    if (j == 0) wsC[bid] = C;
}

__global__ __launch_bounds__(256) void crf_finish(
        const float* __restrict__ unary, const int* __restrict__ labels,
        const float* __restrict__ A, const float* __restrict__ wsState,
        const float* __restrict__ wsC, float* __restrict__ out) {
    const int b   = blockIdx.x;
    const int tid = threadIdx.x;
    const float* ub = unary + (size_t)b * Tn * Pn;
    const int*  lb  = labels + b * Tn;

    // emission + transition label scores
    float partial = 0.f;
    for (int t = tid; t < Tn; t += 256) {
        int lab = lb[t];
        partial += ub[(size_t)t * Pn + lab];
        if (t > 0) {
            int lp = lb[t - 1];
            partial += A[lp * Pn + lab];
        }
    }
    __shared__ float red[256];
    red[tid] = partial;
    __syncthreads();
#pragma unroll
    for (int off = 128; off > 0; off >>= 1) {
        if (tid < off) red[tid] += red[tid + off];
        __syncthreads();
    }
    // logZ from the two half-chain states: lse = Cf + Cb + log(dot(pf, gb))
    if (tid < 64) {
        float d = wsState[(size_t)(2 * b) * Pn + tid] *
                  wsState[(size_t)(2 * b + 1) * Pn + tid];
        d = wave_sum64(d);
        if (tid == 0) {
            float logZ = wsC[2 * b] + wsC[2 * b + 1] + __logf(d);
            float nll_b = logZ - red[0];
            atomicAdd(out, nll_b * (1.0f / 256.0f));
        }
    }
}

extern "C" void kernel_launch(void* const* d_in, const int* in_sizes, int n_in,
                              void* d_out, int out_size, void* d_ws, size_t ws_size,
                              hipStream_t stream) {
    const float* unary  = (const float*)d_in[0];
    const int*   labels = (const int*)d_in[1];
    const float* A      = (const float*)d_in[2];

    float* wsState = (float*)d_ws;              // 512 * 64 floats
    float* wsC     = wsState + 512 * Pn;        // 512 floats

    hipMemsetAsync(d_out, 0, sizeof(float), stream);
    crf_chain<<<512, 64, 0, stream>>>(unary, A, wsState, wsC);
    crf_finish<<<Bn, 256, 0, stream>>>(unary, labels, A, wsState, wsC,
                                       (float*)d_out);
}

// Round 2
// 407.145 us; speedup vs baseline: 1.2661x; 1.2661x over previous
//
#include <hip/hip_runtime.h>

#define Bn 256
#define Tn 2048
#define Pn 64

typedef float f32x2 __attribute__((ext_vector_type(2)));
typedef float f32x4 __attribute__((ext_vector_type(4)));

// ---------------------------------------------------------------------------
// Linear-chain CRF mean NLL.  nll = mean_b( logZ_b - emit_b - trans_b )
// k1 crf_chain: 512 waves (block=1 wave). Block 2b = fwd alpha chain (1024
//   steps), 2b+1 = bwd gamma chain (1022 steps + bare matvec). State in
//   linear space p[j]=exp(alpha[j]-C); per step: 64x64 matvec via
//   v_pk_fma_f32 (32 packed FMAs, 8 indep accumulators) fed by 16 broadcast
//   ds_read_b128. Renorm by lane-0 value every 4 steps (no shuffle tree).
// k2 crf_scores: 2048 blocks x 256 thr, 1 timestep/thread -> label scores.
// k3 crf_logz: 256 waves, midpoint dot -> logZ, atomicAdd mean.
// ---------------------------------------------------------------------------

__device__ __forceinline__ void pk_fma(f32x2& acc, f32x2 a, f32x2 b) {
    asm("v_pk_fma_f32 %0, %1, %2, %0" : "+v"(acc) : "v"(a), "v"(b));
}
__device__ __forceinline__ f32x2 pk_mul(f32x2 a, f32x2 b) {
    f32x2 d;
    asm("v_pk_mul_f32 %0, %1, %2" : "=v"(d) : "v"(a), "v"(b));
    return d;
}
__device__ __forceinline__ f32x2 pk_add(f32x2 a, f32x2 b) {
    f32x2 d;
    asm("v_pk_add_f32 %0, %1, %2" : "=v"(d) : "v"(a), "v"(b));
    return d;
}

// 64-dot per lane: sum_i sbuf[i] * eA2[i/2][i%2], fully unrolled.
__device__ __forceinline__ float matvec64(const f32x4* sb, const f32x2* eA2) {
    f32x2 acc[8];
#pragma unroll
    for (int blk = 0; blk < 16; ++blk) {
        f32x4 pv = sb[blk];
        f32x2 lo = pv.xy;
        f32x2 hi = pv.zw;
        if (blk < 4) {
            acc[(2 * blk) & 7]     = pk_mul(lo, eA2[2 * blk]);
            acc[(2 * blk + 1) & 7] = pk_mul(hi, eA2[2 * blk + 1]);
        } else {
            pk_fma(acc[(2 * blk) & 7],     lo, eA2[2 * blk]);
            pk_fma(acc[(2 * blk + 1) & 7], hi, eA2[2 * blk + 1]);
        }
    }
    f32x2 r0 = pk_add(acc[0], acc[1]);
    f32x2 r1 = pk_add(acc[2], acc[3]);
    f32x2 r2 = pk_add(acc[4], acc[5]);
    f32x2 r3 = pk_add(acc[6], acc[7]);
    r0 = pk_add(r0, r1);
    r2 = pk_add(r2, r3);
    r0 = pk_add(r0, r2);
    return r0.x + r0.y;
}

__device__ __forceinline__ float lane0_bcast(float v) {
    return __int_as_float(__builtin_amdgcn_readfirstlane(__float_as_int(v)));
}

__global__ __launch_bounds__(64) void crf_chain(
        const float* __restrict__ unary, const float* __restrict__ A,
        float* __restrict__ wsState, float* __restrict__ wsC) {
    const int bid = blockIdx.x;
    const int b   = bid >> 1;
    const int dir = bid & 1;   // 0 = forward, 1 = backward
    const int j   = threadIdx.x;

    __shared__ float pbuf[Pn] __attribute__((aligned(16)));
    float* pb = pbuf;
    const f32x4* pb4 = (const f32x4*)pbuf;

    // lane j: fwd holds column j of exp(A); bwd holds row j. Packed pairs.
    f32x2 eA2[32];
#pragma unroll
    for (int m = 0; m < 32; ++m) {
        int i0 = 2 * m, i1 = 2 * m + 1;
        float a0 = (dir == 0) ? A[i0 * Pn + j] : A[j * Pn + i0];
        float a1 = (dir == 0) ? A[i1 * Pn + j] : A[j * Pn + i1];
        f32x2 t = {__expf(a0), __expf(a1)};
        eA2[m] = t;
    }

    const float* ub = unary + (size_t)b * Tn * Pn;

    float p, C;
    {
        const int t0 = (dir == 0) ? 0 : (Tn - 1);
        float u0 = ub[(size_t)t0 * Pn + j];
        // init renorm: subtract lane0's value (cheap, overflow-safe)
        float m0 = lane0_bcast(u0);
        p = __expf(u0 - m0);
        C = m0;
    }
    pb[j] = p;

    const ptrdiff_t stride = (dir == 0) ? (ptrdiff_t)Pn : -(ptrdiff_t)Pn;
    const float* up = ub + j + ((dir == 0) ? (ptrdiff_t)Pn
                                           : (ptrdiff_t)(Tn - 2) * Pn);

    // register prefetch queue, depth 8
    float uq[8];
#pragma unroll
    for (int k = 0; k < 8; ++k) uq[k] = up[stride * k];

    const int nquad = (dir == 0) ? 128 : 127;   // x8 steps

    for (int q = 0; q < nquad; ++q) {
#pragma unroll
        for (int k = 0; k < 8; ++k) {
            float eu = __expf(uq[k]);
            uq[k] = up[stride * (8 + k)];       // prefetch step s+8
            float s = matvec64(pb4, eA2);
            p = s * eu;
            if ((k & 3) == 3) {                 // every 4 steps: renorm by p0
                float p0 = lane0_bcast(p);
                p *= __builtin_amdgcn_rcpf(p0);
                C += __logf(p0);
            }
            pb[j] = p;
        }
        up += stride * 8;
    }

    if (dir == 1) {
        // tail: 6 steps (uq[0..5] hold steps 1016..1021)
#pragma unroll
        for (int k = 0; k < 6; ++k) {
            float eu = __expf(uq[k]);
            float s = matvec64(pb4, eA2);
            p = s * eu;
            if (k == 3) {
                float p0 = lane0_bcast(p);
                p *= __builtin_amdgcn_rcpf(p0);
                C += __logf(p0);
            }
            pb[j] = p;
        }
        // bare matvec (transition only, no emission) -> q_1024
        p = matvec64(pb4, eA2);
    }

    wsState[(size_t)bid * Pn + j] = p;
    if (j == 0) wsC[bid] = C;
}

__global__ __launch_bounds__(256) void crf_scores(
        const float* __restrict__ unary, const int* __restrict__ labels,
        const float* __restrict__ A, float* __restrict__ out) {
    const int bb = blockIdx.x >> 3;
    const int t  = (blockIdx.x & 7) * 256 + threadIdx.x;
    const int* lb = labels + bb * Tn;

    int lab = lb[t];
    float s = unary[((size_t)bb * Tn + t) * Pn + lab];
    if (t > 0) s += A[lb[t - 1] * Pn + lab];

    __shared__ float red[256];
    red[threadIdx.x] = s;
    __syncthreads();
#pragma unroll
    for (int off = 128; off > 0; off >>= 1) {
        if (threadIdx.x < off) red[threadIdx.x] += red[threadIdx.x + off];
        __syncthreads();
    }
    if (threadIdx.x == 0) atomicAdd(out, -red[0] * (1.0f / Bn));
}

__global__ __launch_bounds__(64) void crf_logz(
        const float* __restrict__ wsState, const float* __restrict__ wsC,
        float* __restrict__ out) {
    const int b = blockIdx.x;
    const int j = threadIdx.x;
    float d = wsState[(size_t)(2 * b) * Pn + j] *
              wsState[(size_t)(2 * b + 1) * Pn + j];
#pragma unroll
    for (int off = 32; off > 0; off >>= 1) d += __shfl_xor(d, off, 64);
    if (j == 0) {
        float logZ = wsC[2 * b] + wsC[2 * b + 1] + __logf(d);
        atomicAdd(out, logZ * (1.0f / Bn));
    }
}

extern "C" void kernel_launch(void* const* d_in, const int* in_sizes, int n_in,
                              void* d_out, int out_size, void* d_ws, size_t ws_size,
                              hipStream_t stream) {
    const float* unary  = (const float*)d_in[0];
    const int*   labels = (const int*)d_in[1];
    const float* A      = (const float*)d_in[2];

    float* wsState = (float*)d_ws;              // 512 * 64 floats
    float* wsC     = wsState + 512 * Pn;        // 512 floats

    hipMemsetAsync(d_out, 0, sizeof(float), stream);
    crf_chain<<<512, 64, 0, stream>>>(unary, A, wsState, wsC);
    crf_scores<<<Bn * 8, 256, 0, stream>>>(unary, labels, A, (float*)d_out);
    crf_logz<<<Bn, 64, 0, stream>>>(wsState, wsC, (float*)d_out);
}